// Round 1
// 4456.612 us; speedup vs baseline: 1.6366x; 1.6366x over previous
//
#include <hip/hip_runtime.h>

// AFNO2D: y = irfft2_ortho( MLP( rfft2_ortho(x) ) ) + x
// B=8, H=128, W=128, C=768, NUM_BLOCKS=8, bs=96, HSF=1, lambda=0.01
// HARD_FRAC=1.0 -> all modes kept, so the MLP is applied identically to every
// (kh,kw) mode => H-spectrum ORDER is irrelevant => use DIF fwd (natural->bitrev)
// + DIT inv (bitrev->natural), no bit-reversal pass.

#define B_DIM 8
#define H_DIM 128
#define W_DIM 128
#define C_DIM 768
#define WF    65
#define NBLK  8
#define BS    96
#define LAMBDA 0.01f
#define TWO_PI_OVER_N 0.04908738521234052f   // 2*pi/128

// ---------------------------------------------------------------------------
// K1: rfft along W (direct DFT, 65 outputs from 128 reals), fold 1/128 (ortho fwd)
// grid: (B*H) * 12 c-tiles of 64 ; block 256
// ---------------------------------------------------------------------------
__global__ __launch_bounds__(256) void k1_rfft_w(const float* __restrict__ x,
                                                 float2* __restrict__ S) {
    const int blk   = blockIdx.x;
    const int ctile = blk % 12;
    const int bh    = blk / 12;          // b*128 + h
    const int c0    = ctile * 64;

    __shared__ float xs[W_DIM][64];
    __shared__ float cs[128], sn[128];

    const int tid = threadIdx.x;
    if (tid < 128) {
        float sv, cv;
        sincosf(TWO_PI_OVER_N * (float)tid, &sv, &cv);
        cs[tid] = cv; sn[tid] = sv;
    }
    const size_t xbase = (size_t)bh * (W_DIM * C_DIM) + c0;
    for (int idx = tid; idx < W_DIM * 64; idx += 256) {
        int w = idx >> 6, c = idx & 63;
        xs[w][c] = x[xbase + (size_t)w * C_DIM + c];
    }
    __syncthreads();

    const int c   = tid & 63;
    const int kw0 = tid >> 6;            // 0..3 (wave-uniform)
    for (int kw = kw0; kw <= 64; kw += 4) {
        float ar = 0.f, ai = 0.f;
        for (int w = 0; w < 128; ++w) {
            int t = (kw * w) & 127;
            float v = xs[w][c];
            ar = fmaf(v, cs[t], ar);
            ai = fmaf(-v, sn[t], ai);
        }
        S[((size_t)bh * WF + kw) * C_DIM + c0 + c] =
            make_float2(ar * 0.0078125f, ai * 0.0078125f);
    }
}

// ---------------------------------------------------------------------------
// K2/K4: radix-2 in-LDS FFT along H (128-pt complex), 32 columns per block.
// INV=false: DIF, e^{-i}, natural-in -> bitrev-out, no scale.
// INV=true : DIT, e^{+i}, bitrev-in -> natural-out, scale 1/128.
// grid: B*WF*24 ; block 256
// ---------------------------------------------------------------------------
template <bool INV>
__global__ __launch_bounds__(256) void k_fft_h(float2* __restrict__ S) {
    const int blk   = blockIdx.x;
    const int ctile = blk % 24;
    const int rest  = blk / 24;
    const int kw    = rest % WF;
    const int b     = rest / WF;
    const int c0    = ctile * 32;

    __shared__ float2 zs[H_DIM][33];     // pad 32->33 to spread banks across h
    __shared__ float cs[64], sn[64];     // twiddle idx t<<(6-ls) is always < 64

    const int tid = threadIdx.x;
    if (tid < 64) {
        float sv, cv;
        sincosf(TWO_PI_OVER_N * (float)tid, &sv, &cv);
        cs[tid] = cv; sn[tid] = sv;
    }
    const size_t base = (((size_t)b * H_DIM) * WF + kw) * C_DIM + c0;
    const size_t hstr = (size_t)WF * C_DIM;
    for (int idx = tid; idx < H_DIM * 32; idx += 256) {
        int h = idx >> 5, c = idx & 31;
        zs[h][c] = S[base + (size_t)h * hstr + c];
    }
    __syncthreads();

    const int c  = tid & 31;
    const int j0 = tid >> 5;             // 0..7
    #pragma unroll
    for (int s = 0; s < 7; ++s) {
        const int ls = INV ? s : (6 - s);    // log2(half-span m)
        const int m  = 1 << ls;
        #pragma unroll
        for (int jj = 0; jj < 8; ++jj) {
            const int j  = j0 + jj * 8;      // butterfly id 0..63 (disjoint)
            const int t  = j & (m - 1);
            const int i0 = 2 * j - t;        // = (j/m)*2m + t
            const int i1 = i0 + m;
            const int tw = t << (6 - ls);    // t * 64/m  (e^{-+2pi i t/(2m)})
            float2 a  = zs[i0][c];
            float2 bv = zs[i1][c];
            const float cv = cs[tw], sv = sn[tw];
            if (!INV) {
                // DIF: out0 = a+b ; out1 = (a-b) * (cos - i sin)
                float dx = a.x - bv.x, dy = a.y - bv.y;
                zs[i0][c] = make_float2(a.x + bv.x, a.y + bv.y);
                zs[i1][c] = make_float2(fmaf(dx, cv,  dy * sv),
                                        fmaf(dy, cv, -dx * sv));
            } else {
                // DIT: bt = b * (cos + i sin) ; out0 = a+bt ; out1 = a-bt
                float btx = fmaf(bv.x, cv, -bv.y * sv);
                float bty = fmaf(bv.y, cv,  bv.x * sv);
                zs[i0][c] = make_float2(a.x + btx, a.y + bty);
                zs[i1][c] = make_float2(a.x - btx, a.y - bty);
            }
        }
        __syncthreads();
    }

    for (int idx = tid; idx < H_DIM * 32; idx += 256) {
        int h = idx >> 5, cc = idx & 31;
        float2 v = zs[h][cc];
        if (INV) { v.x *= 0.0078125f; v.y *= 0.0078125f; }
        S[base + (size_t)h * hstr + cc] = v;
    }
}

// ---------------------------------------------------------------------------
// K3: per-mode block-diagonal complex 2-layer MLP, in-place on S.
// Register tile: 3 outputs x 4 positions per thread (24 f32 accumulators),
// 48 FMA per inner-i iteration per 6 global + 4 broadcast-LDS loads.
// grid: (66560/32 position tiles, 8 blocks) ; block 256
// ---------------------------------------------------------------------------
__device__ __forceinline__ float softshrinkf(float v) {
    return v > LAMBDA ? v - LAMBDA : (v < -LAMBDA ? v + LAMBDA : 0.f);
}

__global__ __launch_bounds__(256) void k3_mlp(float2* __restrict__ S,
                                              const float* __restrict__ w1,
                                              const float* __restrict__ b1,
                                              const float* __restrict__ w2,
                                              const float* __restrict__ b2) {
    const int n     = blockIdx.y;
    const int pbase = blockIdx.x * 32;
    const int c0    = n * BS;

    __shared__ float2 xin[32][BS];
    __shared__ float2 o1s[32][BS];

    const int tid = threadIdx.x;
    for (int idx = tid; idx < 32 * BS; idx += 256) {
        int p = idx / BS, c = idx - p * BS;
        xin[p][c] = S[(size_t)(pbase + p) * C_DIM + c0 + c];
    }
    __syncthreads();

    const int oq = tid & 31;   // outputs oq, oq+32, oq+64
    const int pq = tid >> 5;   // positions pq + 8*jj, jj=0..3

    float ar[3][4], ai[3][4];
    #pragma unroll
    for (int k = 0; k < 3; ++k)
        #pragma unroll
        for (int jj = 0; jj < 4; ++jj) { ar[k][jj] = 0.f; ai[k][jj] = 0.f; }

    // layer 1: o1 = relu( x * (W1r + i W1i) + (b1r + i b1i) )
    const float* W1r = w1 + (size_t)n * BS * BS + oq;
    const float* W1i = w1 + (size_t)(NBLK + n) * BS * BS + oq;
    for (int i = 0; i < BS; ++i) {
        float2 z0 = xin[pq][i];
        float2 z1 = xin[pq + 8][i];
        float2 z2 = xin[pq + 16][i];
        float2 z3 = xin[pq + 24][i];
        #pragma unroll
        for (int k = 0; k < 3; ++k) {
            float wr = W1r[i * BS + 32 * k];
            float wi = W1i[i * BS + 32 * k];
            ar[k][0] = fmaf(z0.x, wr, fmaf(-z0.y, wi, ar[k][0]));
            ai[k][0] = fmaf(z0.y, wr, fmaf( z0.x, wi, ai[k][0]));
            ar[k][1] = fmaf(z1.x, wr, fmaf(-z1.y, wi, ar[k][1]));
            ai[k][1] = fmaf(z1.y, wr, fmaf( z1.x, wi, ai[k][1]));
            ar[k][2] = fmaf(z2.x, wr, fmaf(-z2.y, wi, ar[k][2]));
            ai[k][2] = fmaf(z2.y, wr, fmaf( z2.x, wi, ai[k][2]));
            ar[k][3] = fmaf(z3.x, wr, fmaf(-z3.y, wi, ar[k][3]));
            ai[k][3] = fmaf(z3.y, wr, fmaf( z3.x, wi, ai[k][3]));
        }
    }
    #pragma unroll
    for (int k = 0; k < 3; ++k) {
        const int o = oq + 32 * k;
        const float br = b1[n * BS + o], bi = b1[(NBLK + n) * BS + o];
        #pragma unroll
        for (int jj = 0; jj < 4; ++jj)
            o1s[pq + 8 * jj][o] = make_float2(fmaxf(ar[k][jj] + br, 0.f),
                                              fmaxf(ai[k][jj] + bi, 0.f));
    }
    __syncthreads();

    #pragma unroll
    for (int k = 0; k < 3; ++k)
        #pragma unroll
        for (int jj = 0; jj < 4; ++jj) { ar[k][jj] = 0.f; ai[k][jj] = 0.f; }

    // layer 2: o2 = softshrink( o1 * (W2r + i W2i) + b2 )
    const float* W2r = w2 + (size_t)n * BS * BS + oq;
    const float* W2i = w2 + (size_t)(NBLK + n) * BS * BS + oq;
    for (int i = 0; i < BS; ++i) {       // i = hidden index
        float2 z0 = o1s[pq][i];
        float2 z1 = o1s[pq + 8][i];
        float2 z2 = o1s[pq + 16][i];
        float2 z3 = o1s[pq + 24][i];
        #pragma unroll
        for (int k = 0; k < 3; ++k) {
            float wr = W2r[i * BS + 32 * k];
            float wi = W2i[i * BS + 32 * k];
            ar[k][0] = fmaf(z0.x, wr, fmaf(-z0.y, wi, ar[k][0]));
            ai[k][0] = fmaf(z0.y, wr, fmaf( z0.x, wi, ai[k][0]));
            ar[k][1] = fmaf(z1.x, wr, fmaf(-z1.y, wi, ar[k][1]));
            ai[k][1] = fmaf(z1.y, wr, fmaf( z1.x, wi, ai[k][1]));
            ar[k][2] = fmaf(z2.x, wr, fmaf(-z2.y, wi, ar[k][2]));
            ai[k][2] = fmaf(z2.y, wr, fmaf( z2.x, wi, ai[k][2]));
            ar[k][3] = fmaf(z3.x, wr, fmaf(-z3.y, wi, ar[k][3]));
            ai[k][3] = fmaf(z3.y, wr, fmaf( z3.x, wi, ai[k][3]));
        }
    }
    #pragma unroll
    for (int k = 0; k < 3; ++k) {
        const int o = oq + 32 * k;
        const float br = b2[n * BS + o], bi = b2[(NBLK + n) * BS + o];
        #pragma unroll
        for (int jj = 0; jj < 4; ++jj) {
            float vr = softshrinkf(ar[k][jj] + br);
            float vi = softshrinkf(ai[k][jj] + bi);
            S[(size_t)(pbase + pq + 8 * jj) * C_DIM + c0 + o] = make_float2(vr, vi);
        }
    }
}

// ---------------------------------------------------------------------------
// K5: C2R inverse rfft along W + bias add.
// y[w] = Z0.r + (-1)^w Z64.r + 2*sum_{k=1..63}(Zk.r cos - Zk.i sin) ; + x
// grid: (B*H) * 24 c-tiles of 32 ; block 256
// ---------------------------------------------------------------------------
__global__ __launch_bounds__(256) void k5_irfft_w(const float2* __restrict__ S,
                                                  const float* __restrict__ x,
                                                  float* __restrict__ out) {
    const int blk   = blockIdx.x;
    const int ctile = blk % 24;
    const int bh    = blk / 24;
    const int c0    = ctile * 32;

    __shared__ float2 zs[WF][32];
    __shared__ float cs[128], sn[128];

    const int tid = threadIdx.x;
    if (tid < 128) {
        float sv, cv;
        sincosf(TWO_PI_OVER_N * (float)tid, &sv, &cv);
        cs[tid] = cv; sn[tid] = sv;
    }
    const size_t sbase = (size_t)bh * WF * C_DIM + c0;
    for (int idx = tid; idx < WF * 32; idx += 256) {
        int k = idx >> 5, c = idx & 31;
        zs[k][c] = S[sbase + (size_t)k * C_DIM + c];
    }
    __syncthreads();

    const int c  = tid & 31;
    const int w0 = tid >> 5;             // 0..7
    const size_t obase = (size_t)bh * (W_DIM * C_DIM) + c0;
    for (int w = w0; w < 128; w += 8) {
        float sacc = zs[0][c].x + ((w & 1) ? -zs[64][c].x : zs[64][c].x);
        for (int k = 1; k < 64; ++k) {
            int t = (k * w) & 127;
            float2 z = zs[k][c];
            sacc = fmaf(2.f * z.x, cs[t], fmaf(-2.f * z.y, sn[t], sacc));
        }
        size_t oidx = obase + (size_t)w * C_DIM + c;
        out[oidx] = sacc + x[oidx];
    }
}

// ---------------------------------------------------------------------------
extern "C" void kernel_launch(void* const* d_in, const int* in_sizes, int n_in,
                              void* d_out, int out_size, void* d_ws, size_t ws_size,
                              hipStream_t stream) {
    const float* x  = (const float*)d_in[0];
    const float* w1 = (const float*)d_in[1];
    const float* b1 = (const float*)d_in[2];
    const float* w2 = (const float*)d_in[3];
    const float* b2 = (const float*)d_in[4];
    float* out = (float*)d_out;
    float2* S  = (float2*)d_ws;          // (B,H,WF,C) complex64 = 409 MB

    k1_rfft_w<<<dim3(B_DIM * H_DIM * 12), dim3(256), 0, stream>>>(x, S);
    k_fft_h<false><<<dim3(B_DIM * WF * 24), dim3(256), 0, stream>>>(S);
    k3_mlp<<<dim3((B_DIM * H_DIM * WF) / 32, NBLK), dim3(256), 0, stream>>>(S, w1, b1, w2, b2);
    k_fft_h<true><<<dim3(B_DIM * WF * 24), dim3(256), 0, stream>>>(S);
    k5_irfft_w<<<dim3(B_DIM * H_DIM * 24), dim3(256), 0, stream>>>(S, x, out);
}

// Round 2
// 2525.910 us; speedup vs baseline: 2.8876x; 1.7644x over previous
//
#include <hip/hip_runtime.h>

// AFNO2D: y = irfft2_ortho( MLP( rfft2_ortho(x) ) ) + x
// B=8, H=128, W=128, C=768, NUM_BLOCKS=8, bs=96, HSF=1, lambda=0.01
// HARD_FRAC=1.0 -> all modes kept, so the MLP is applied identically to every
// (kh,kw) mode => H-spectrum ORDER is irrelevant => DIF fwd (natural->bitrev)
// + DIT inv (bitrev->natural) along H, no bit-reversal pass.
// Along W: real-pair packing -> one 128-pt complex FFT serves two channels.
// Hermitian unpack/repack reads bitrev indices directly from LDS.

#define B_DIM 8
#define H_DIM 128
#define W_DIM 128
#define C_DIM 768
#define WF    65
#define NBLK  8
#define BS    96
#define LAMBDA 0.01f
#define TWO_PI_OVER_N 0.04908738521234052f   // 2*pi/128

__device__ __forceinline__ int brev7(int v) { return (int)(__brev((unsigned)v) >> 25); }

// ---------------------------------------------------------------------------
// K1: rfft along W via packed complex radix-2 FFT. fold 1/128 (ortho fwd).
// Each block: one (b,h) row, 32 channels = 16 packed complex columns.
// grid: (B*H) * 24 ; block 256
// ---------------------------------------------------------------------------
__global__ __launch_bounds__(256) void k1_rfft_w(const float* __restrict__ x,
                                                 float2* __restrict__ S) {
    const int blk   = blockIdx.x;
    const int ctile = blk % 24;
    const int bh    = blk / 24;          // b*128 + h
    const int c0    = ctile * 32;        // 32 real channels = 16 complex pairs

    __shared__ float2 zs[W_DIM][17];     // pad 16->17
    __shared__ float cs[64], sn[64];

    const int tid = threadIdx.x;
    if (tid < 64) {
        float sv, cv;
        sincosf(TWO_PI_OVER_N * (float)tid, &sv, &cv);
        cs[tid] = cv; sn[tid] = sv;
    }
    // pack: z[w] = x[w][c0+2u] + i x[w][c0+2u+1]  (contiguous float2 load)
    const float2* xp = (const float2*)(x + (size_t)bh * (W_DIM * C_DIM) + c0);
    for (int idx = tid; idx < W_DIM * 16; idx += 256) {
        int w = idx >> 4, u = idx & 15;
        zs[w][u] = xp[(size_t)w * (C_DIM / 2) + u];
    }
    __syncthreads();

    // 128-pt DIF FFT (e^{-i}), natural in -> bitrev out
    const int u  = tid & 15;
    const int j0 = tid >> 4;             // 0..15
    #pragma unroll
    for (int s = 0; s < 7; ++s) {
        const int ls = 6 - s;
        const int m  = 1 << ls;
        #pragma unroll
        for (int jj = 0; jj < 4; ++jj) {
            const int j  = j0 + jj * 16;     // butterfly id 0..63
            const int t  = j & (m - 1);
            const int i0 = 2 * j - t;
            const int i1 = i0 + m;
            const int tw = t << (6 - ls);
            float2 a = zs[i0][u], b = zs[i1][u];
            const float cv = cs[tw], sv = sn[tw];
            float dx = a.x - b.x, dy = a.y - b.y;
            zs[i0][u] = make_float2(a.x + b.x, a.y + b.y);
            zs[i1][u] = make_float2(fmaf(dx, cv,  dy * sv),
                                    fmaf(dy, cv, -dx * sv));
        }
        __syncthreads();
    }

    // Hermitian unpack: A[k]=(Z[k]+conj(Z[-k]))/2, B[k]=(Z[k]-conj(Z[-k]))/(2i)
    for (int pos = tid; pos < WF * 16; pos += 256) {
        int kw = pos >> 4, uu = pos & 15;
        float2 Za = zs[brev7(kw)][uu];
        float2 Zb = zs[brev7((128 - kw) & 127)][uu];
        const float sc = 0.5f * 0.0078125f;
        float xcx = (Za.x + Zb.x) * sc;
        float xcy = (Za.y - Zb.y) * sc;
        float xdx = (Za.y + Zb.y) * sc;
        float xdy = (Zb.x - Za.x) * sc;
        float4* Srow = (float4*)(S + ((size_t)bh * WF + kw) * C_DIM + c0);
        Srow[uu] = make_float4(xcx, xcy, xdx, xdy);
    }
}

// ---------------------------------------------------------------------------
// K2/K4: radix-2 in-LDS FFT along H (128-pt complex), 32 columns per block.
// INV=false: DIF, e^{-i}, natural-in -> bitrev-out, no scale.
// INV=true : DIT, e^{+i}, bitrev-in -> natural-out, scale 1/128.
// grid: B*WF*24 ; block 256
// ---------------------------------------------------------------------------
template <bool INV>
__global__ __launch_bounds__(256) void k_fft_h(float2* __restrict__ S) {
    const int blk   = blockIdx.x;
    const int ctile = blk % 24;
    const int rest  = blk / 24;
    const int kw    = rest % WF;
    const int b     = rest / WF;
    const int c0    = ctile * 32;

    __shared__ float2 zs[H_DIM][33];     // pad 32->33
    __shared__ float cs[64], sn[64];

    const int tid = threadIdx.x;
    if (tid < 64) {
        float sv, cv;
        sincosf(TWO_PI_OVER_N * (float)tid, &sv, &cv);
        cs[tid] = cv; sn[tid] = sv;
    }
    const size_t base = (((size_t)b * H_DIM) * WF + kw) * C_DIM + c0;
    const size_t hstr = (size_t)WF * C_DIM;
    for (int idx = tid; idx < H_DIM * 32; idx += 256) {
        int h = idx >> 5, c = idx & 31;
        zs[h][c] = S[base + (size_t)h * hstr + c];
    }
    __syncthreads();

    const int c  = tid & 31;
    const int j0 = tid >> 5;             // 0..7
    #pragma unroll
    for (int s = 0; s < 7; ++s) {
        const int ls = INV ? s : (6 - s);    // log2(half-span m)
        const int m  = 1 << ls;
        #pragma unroll
        for (int jj = 0; jj < 8; ++jj) {
            const int j  = j0 + jj * 8;      // butterfly id 0..63 (disjoint)
            const int t  = j & (m - 1);
            const int i0 = 2 * j - t;
            const int i1 = i0 + m;
            const int tw = t << (6 - ls);
            float2 a  = zs[i0][c];
            float2 bv = zs[i1][c];
            const float cv = cs[tw], sv = sn[tw];
            if (!INV) {
                float dx = a.x - bv.x, dy = a.y - bv.y;
                zs[i0][c] = make_float2(a.x + bv.x, a.y + bv.y);
                zs[i1][c] = make_float2(fmaf(dx, cv,  dy * sv),
                                        fmaf(dy, cv, -dx * sv));
            } else {
                float btx = fmaf(bv.x, cv, -bv.y * sv);
                float bty = fmaf(bv.y, cv,  bv.x * sv);
                zs[i0][c] = make_float2(a.x + btx, a.y + bty);
                zs[i1][c] = make_float2(a.x - btx, a.y - bty);
            }
        }
        __syncthreads();
    }

    for (int idx = tid; idx < H_DIM * 32; idx += 256) {
        int h = idx >> 5, cc = idx & 31;
        float2 v = zs[h][cc];
        if (INV) { v.x *= 0.0078125f; v.y *= 0.0078125f; }
        S[base + (size_t)h * hstr + cc] = v;
    }
}

// ---------------------------------------------------------------------------
// K3: per-mode block-diagonal complex 2-layer MLP, in-place on S.
// Register tile: 3 outputs x 4 positions per thread (24 f32 accumulators).
// grid: (66560/32 position tiles, 8 blocks) ; block 256
// ---------------------------------------------------------------------------
__device__ __forceinline__ float softshrinkf(float v) {
    return v > LAMBDA ? v - LAMBDA : (v < -LAMBDA ? v + LAMBDA : 0.f);
}

__global__ __launch_bounds__(256) void k3_mlp(float2* __restrict__ S,
                                              const float* __restrict__ w1,
                                              const float* __restrict__ b1,
                                              const float* __restrict__ w2,
                                              const float* __restrict__ b2) {
    const int n     = blockIdx.y;
    const int pbase = blockIdx.x * 32;
    const int c0    = n * BS;

    __shared__ float2 xin[32][BS];
    __shared__ float2 o1s[32][BS];

    const int tid = threadIdx.x;
    for (int idx = tid; idx < 32 * BS; idx += 256) {
        int p = idx / BS, c = idx - p * BS;
        xin[p][c] = S[(size_t)(pbase + p) * C_DIM + c0 + c];
    }
    __syncthreads();

    const int oq = tid & 31;   // outputs oq, oq+32, oq+64
    const int pq = tid >> 5;   // positions pq + 8*jj, jj=0..3

    float ar[3][4], ai[3][4];
    #pragma unroll
    for (int k = 0; k < 3; ++k)
        #pragma unroll
        for (int jj = 0; jj < 4; ++jj) { ar[k][jj] = 0.f; ai[k][jj] = 0.f; }

    const float* W1r = w1 + (size_t)n * BS * BS + oq;
    const float* W1i = w1 + (size_t)(NBLK + n) * BS * BS + oq;
    for (int i = 0; i < BS; ++i) {
        float2 z0 = xin[pq][i];
        float2 z1 = xin[pq + 8][i];
        float2 z2 = xin[pq + 16][i];
        float2 z3 = xin[pq + 24][i];
        #pragma unroll
        for (int k = 0; k < 3; ++k) {
            float wr = W1r[i * BS + 32 * k];
            float wi = W1i[i * BS + 32 * k];
            ar[k][0] = fmaf(z0.x, wr, fmaf(-z0.y, wi, ar[k][0]));
            ai[k][0] = fmaf(z0.y, wr, fmaf( z0.x, wi, ai[k][0]));
            ar[k][1] = fmaf(z1.x, wr, fmaf(-z1.y, wi, ar[k][1]));
            ai[k][1] = fmaf(z1.y, wr, fmaf( z1.x, wi, ai[k][1]));
            ar[k][2] = fmaf(z2.x, wr, fmaf(-z2.y, wi, ar[k][2]));
            ai[k][2] = fmaf(z2.y, wr, fmaf( z2.x, wi, ai[k][2]));
            ar[k][3] = fmaf(z3.x, wr, fmaf(-z3.y, wi, ar[k][3]));
            ai[k][3] = fmaf(z3.y, wr, fmaf( z3.x, wi, ai[k][3]));
        }
    }
    #pragma unroll
    for (int k = 0; k < 3; ++k) {
        const int o = oq + 32 * k;
        const float br = b1[n * BS + o], bi = b1[(NBLK + n) * BS + o];
        #pragma unroll
        for (int jj = 0; jj < 4; ++jj)
            o1s[pq + 8 * jj][o] = make_float2(fmaxf(ar[k][jj] + br, 0.f),
                                              fmaxf(ai[k][jj] + bi, 0.f));
    }
    __syncthreads();

    #pragma unroll
    for (int k = 0; k < 3; ++k)
        #pragma unroll
        for (int jj = 0; jj < 4; ++jj) { ar[k][jj] = 0.f; ai[k][jj] = 0.f; }

    const float* W2r = w2 + (size_t)n * BS * BS + oq;
    const float* W2i = w2 + (size_t)(NBLK + n) * BS * BS + oq;
    for (int i = 0; i < BS; ++i) {
        float2 z0 = o1s[pq][i];
        float2 z1 = o1s[pq + 8][i];
        float2 z2 = o1s[pq + 16][i];
        float2 z3 = o1s[pq + 24][i];
        #pragma unroll
        for (int k = 0; k < 3; ++k) {
            float wr = W2r[i * BS + 32 * k];
            float wi = W2i[i * BS + 32 * k];
            ar[k][0] = fmaf(z0.x, wr, fmaf(-z0.y, wi, ar[k][0]));
            ai[k][0] = fmaf(z0.y, wr, fmaf( z0.x, wi, ai[k][0]));
            ar[k][1] = fmaf(z1.x, wr, fmaf(-z1.y, wi, ar[k][1]));
            ai[k][1] = fmaf(z1.y, wr, fmaf( z1.x, wi, ai[k][1]));
            ar[k][2] = fmaf(z2.x, wr, fmaf(-z2.y, wi, ar[k][2]));
            ai[k][2] = fmaf(z2.y, wr, fmaf( z2.x, wi, ai[k][2]));
            ar[k][3] = fmaf(z3.x, wr, fmaf(-z3.y, wi, ar[k][3]));
            ai[k][3] = fmaf(z3.y, wr, fmaf( z3.x, wi, ai[k][3]));
        }
    }
    #pragma unroll
    for (int k = 0; k < 3; ++k) {
        const int o = oq + 32 * k;
        const float br = b2[n * BS + o], bi = b2[(NBLK + n) * BS + o];
        #pragma unroll
        for (int jj = 0; jj < 4; ++jj) {
            float vr = softshrinkf(ar[k][jj] + br);
            float vi = softshrinkf(ai[k][jj] + bi);
            S[(size_t)(pbase + pq + 8 * jj) * C_DIM + c0 + o] = make_float2(vr, vi);
        }
    }
}

// ---------------------------------------------------------------------------
// K5: C2R inverse rfft along W via packed complex radix-2 FFT, + bias add.
// Rebuild full packed spectrum Z[k] = A[k] + i B[k] (two channels) from the
// 65 stored modes (imag of DC/Nyquist zeroed = pocketfft C2R convention),
// conj-twiddle DIF (unscaled IDFT, natural->bitrev), y[br(p)] = zs[p].
// grid: (B*H) * 24 ; block 256
// ---------------------------------------------------------------------------
__global__ __launch_bounds__(256) void k5_irfft_w(const float2* __restrict__ S,
                                                  const float* __restrict__ x,
                                                  float* __restrict__ out) {
    const int blk   = blockIdx.x;
    const int ctile = blk % 24;
    const int bh    = blk / 24;
    const int c0    = ctile * 32;        // 32 real channels = 16 pairs

    __shared__ float2 zs[W_DIM][17];
    __shared__ float cs[64], sn[64];

    const int tid = threadIdx.x;
    if (tid < 64) {
        float sv, cv;
        sincosf(TWO_PI_OVER_N * (float)tid, &sv, &cv);
        cs[tid] = cv; sn[tid] = sv;
    }
    for (int pos = tid; pos < WF * 16; pos += 256) {
        int kw = pos >> 4, uu = pos & 15;
        float4 q = ((const float4*)(S + ((size_t)bh * WF + kw) * C_DIM + c0))[uu];
        float xcx = q.x, xcy = q.y, xdx = q.z, xdy = q.w;
        if (kw == 0 || kw == 64) { xcy = 0.f; xdy = 0.f; }
        zs[kw][uu] = make_float2(xcx - xdy, xcy + xdx);        // Z[k] = A + iB
        if (kw >= 1 && kw <= 63)                               // Z[128-k] = conj(A)+i conj(B)
            zs[128 - kw][uu] = make_float2(xcx + xdy, xdx - xcy);
    }
    __syncthreads();

    // 128-pt DIF with conj twiddles (e^{+i}): unscaled IDFT, natural->bitrev
    const int u  = tid & 15;
    const int j0 = tid >> 4;
    #pragma unroll
    for (int s = 0; s < 7; ++s) {
        const int ls = 6 - s;
        const int m  = 1 << ls;
        #pragma unroll
        for (int jj = 0; jj < 4; ++jj) {
            const int j  = j0 + jj * 16;
            const int t  = j & (m - 1);
            const int i0 = 2 * j - t;
            const int i1 = i0 + m;
            const int tw = t << (6 - ls);
            float2 a = zs[i0][u], b = zs[i1][u];
            const float cv = cs[tw], sv = sn[tw];
            float dx = a.x - b.x, dy = a.y - b.y;
            zs[i0][u] = make_float2(a.x + b.x, a.y + b.y);
            zs[i1][u] = make_float2(fmaf(dx, cv, -dy * sv),
                                    fmaf(dy, cv,  dx * sv));
        }
        __syncthreads();
    }

    // y[br(p)] = (Re zs[p], Im zs[p]) for the channel pair; add residual x
    const size_t obase = (size_t)bh * (W_DIM * C_DIM) + c0;
    for (int pos = tid; pos < W_DIM * 16; pos += 256) {
        int p = pos >> 4, uu = pos & 15;
        int w = brev7(p);
        float2 v  = zs[p][uu];
        float2 xv = ((const float2*)(x + obase + (size_t)w * C_DIM))[uu];
        ((float2*)(out + obase + (size_t)w * C_DIM))[uu] =
            make_float2(v.x + xv.x, v.y + xv.y);
    }
}

// ---------------------------------------------------------------------------
extern "C" void kernel_launch(void* const* d_in, const int* in_sizes, int n_in,
                              void* d_out, int out_size, void* d_ws, size_t ws_size,
                              hipStream_t stream) {
    const float* x  = (const float*)d_in[0];
    const float* w1 = (const float*)d_in[1];
    const float* b1 = (const float*)d_in[2];
    const float* w2 = (const float*)d_in[3];
    const float* b2 = (const float*)d_in[4];
    float* out = (float*)d_out;
    float2* S  = (float2*)d_ws;          // (B,H,WF,C) complex64 = 409 MB

    k1_rfft_w<<<dim3(B_DIM * H_DIM * 24), dim3(256), 0, stream>>>(x, S);
    k_fft_h<false><<<dim3(B_DIM * WF * 24), dim3(256), 0, stream>>>(S);
    k3_mlp<<<dim3((B_DIM * H_DIM * WF) / 32, NBLK), dim3(256), 0, stream>>>(S, w1, b1, w2, b2);
    k_fft_h<true><<<dim3(B_DIM * WF * 24), dim3(256), 0, stream>>>(S);
    k5_irfft_w<<<dim3(B_DIM * H_DIM * 24), dim3(256), 0, stream>>>(S, x, out);
}

// Round 3
// 2291.365 us; speedup vs baseline: 3.1832x; 1.1024x over previous
//
#include <hip/hip_runtime.h>

// AFNO2D: y = irfft2_ortho( MLP( rfft2_ortho(x) ) ) + x
// B=8, H=128, W=128, C=768, NUM_BLOCKS=8, bs=96, HSF=1, lambda=0.01
// HARD_FRAC=1.0 -> all modes kept, so the MLP is applied identically to every
// (kh,kw) mode => spectral ORDER is irrelevant => DIF fwd (natural->bitrev)
// + DIT inv along H, packed-real radix-2 FFT along W.
// MLP runs on the matrix cores: bf16 split-2 (hi+lo), 3-pass MFMA, fp32 accum.
// Weights are pre-assembled (k0) into transposed bf16 hi/lo B-matrices:
//   B_r = [W_r; -W_i] (cols 0..95 -> o_r),  B_i = [W_i; W_r] (cols -> o_i)
// stored BT[col][k] (k-contiguous) in the first 2.4 MB of d_out (scratch until
// k5 overwrites all of out at the end).

#define B_DIM 8
#define H_DIM 128
#define W_DIM 128
#define C_DIM 768
#define WF    65
#define NBLK  8
#define BS    96
#define LAMBDA 0.01f
#define TWO_PI_OVER_N 0.04908738521234052f   // 2*pi/128

typedef short bf16x8 __attribute__((ext_vector_type(8)));  // 8 bf16 (4 VGPRs)
typedef float f32x4  __attribute__((ext_vector_type(4)));

__device__ __forceinline__ int brev7(int v) { return (int)(__brev((unsigned)v) >> 25); }

__device__ __forceinline__ void split_bf16(float f, short& h, short& l) {
    unsigned u  = __float_as_uint(f);
    unsigned hr = u + 0x7FFFu + ((u >> 16) & 1u);          // RNE to bf16
    h = (short)(hr >> 16);
    float hf = __uint_as_float((hr >> 16) << 16);
    float lo = f - hf;
    unsigned u2 = __float_as_uint(lo);
    unsigned lr = u2 + 0x7FFFu + ((u2 >> 16) & 1u);
    l = (short)(lr >> 16);
}

// ---------------------------------------------------------------------------
// K0: assemble transposed bf16 hi/lo B-matrices into scratch (start of out).
// Layout: mat(L,n,v,part)[col 0..95][k 0..191], part: 0=hi 1=lo.
// grid 2304 x 256  (2*8*2*96*192 = 589824 elements)
// ---------------------------------------------------------------------------
__global__ __launch_bounds__(256) void k0_wconv(const float* __restrict__ w1,
                                                const float* __restrict__ w2,
                                                short* __restrict__ bt) {
    int idx = blockIdx.x * 256 + threadIdx.x;
    int k   = idx % 192;
    int col = (idx / 192) % 96;
    int v   = (idx / (192 * 96)) % 2;
    int n   = (idx / (192 * 96 * 2)) % 8;
    int L   = idx / (192 * 96 * 2 * 8);
    const float* W  = L ? w2 : w1;
    const float* Wr = W + (size_t)n * 9216;
    const float* Wi = W + (size_t)(8 + n) * 9216;
    float val;
    if (v == 0) val = (k < 96) ? Wr[k * 96 + col] : -Wi[(k - 96) * 96 + col];
    else        val = (k < 96) ? Wi[k * 96 + col] :  Wr[(k - 96) * 96 + col];
    short h, l; split_bf16(val, h, l);
    size_t mi = ((size_t)(L * 8 + n) * 2 + v) * 2;
    bt[(mi + 0) * 18432 + col * 192 + k] = h;
    bt[(mi + 1) * 18432 + col * 192 + k] = l;
}

// ---------------------------------------------------------------------------
// K1: rfft along W via packed complex radix-2 FFT. fold 1/128 (ortho fwd).
// grid: (B*H) * 24 ; block 256
// ---------------------------------------------------------------------------
__global__ __launch_bounds__(256) void k1_rfft_w(const float* __restrict__ x,
                                                 float2* __restrict__ S) {
    const int blk   = blockIdx.x;
    const int ctile = blk % 24;
    const int bh    = blk / 24;          // b*128 + h
    const int c0    = ctile * 32;        // 32 real channels = 16 complex pairs

    __shared__ float2 zs[W_DIM][17];     // pad 16->17
    __shared__ float cs[64], sn[64];

    const int tid = threadIdx.x;
    if (tid < 64) {
        float sv, cv;
        sincosf(TWO_PI_OVER_N * (float)tid, &sv, &cv);
        cs[tid] = cv; sn[tid] = sv;
    }
    const float2* xp = (const float2*)(x + (size_t)bh * (W_DIM * C_DIM) + c0);
    for (int idx = tid; idx < W_DIM * 16; idx += 256) {
        int w = idx >> 4, u = idx & 15;
        zs[w][u] = xp[(size_t)w * (C_DIM / 2) + u];
    }
    __syncthreads();

    const int u  = tid & 15;
    const int j0 = tid >> 4;             // 0..15
    #pragma unroll
    for (int s = 0; s < 7; ++s) {
        const int ls = 6 - s;
        const int m  = 1 << ls;
        #pragma unroll
        for (int jj = 0; jj < 4; ++jj) {
            const int j  = j0 + jj * 16;
            const int t  = j & (m - 1);
            const int i0 = 2 * j - t;
            const int i1 = i0 + m;
            const int tw = t << (6 - ls);
            float2 a = zs[i0][u], b = zs[i1][u];
            const float cv = cs[tw], sv = sn[tw];
            float dx = a.x - b.x, dy = a.y - b.y;
            zs[i0][u] = make_float2(a.x + b.x, a.y + b.y);
            zs[i1][u] = make_float2(fmaf(dx, cv,  dy * sv),
                                    fmaf(dy, cv, -dx * sv));
        }
        __syncthreads();
    }

    for (int pos = tid; pos < WF * 16; pos += 256) {
        int kw = pos >> 4, uu = pos & 15;
        float2 Za = zs[brev7(kw)][uu];
        float2 Zb = zs[brev7((128 - kw) & 127)][uu];
        const float sc = 0.5f * 0.0078125f;
        float xcx = (Za.x + Zb.x) * sc;
        float xcy = (Za.y - Zb.y) * sc;
        float xdx = (Za.y + Zb.y) * sc;
        float xdy = (Zb.x - Za.x) * sc;
        float4* Srow = (float4*)(S + ((size_t)bh * WF + kw) * C_DIM + c0);
        Srow[uu] = make_float4(xcx, xcy, xdx, xdy);
    }
}

// ---------------------------------------------------------------------------
// K2/K4: radix-2 in-LDS FFT along H (128-pt complex), 32 columns per block.
// grid: B*WF*24 ; block 256
// ---------------------------------------------------------------------------
template <bool INV>
__global__ __launch_bounds__(256) void k_fft_h(float2* __restrict__ S) {
    const int blk   = blockIdx.x;
    const int ctile = blk % 24;
    const int rest  = blk / 24;
    const int kw    = rest % WF;
    const int b     = rest / WF;
    const int c0    = ctile * 32;

    __shared__ float2 zs[H_DIM][33];
    __shared__ float cs[64], sn[64];

    const int tid = threadIdx.x;
    if (tid < 64) {
        float sv, cv;
        sincosf(TWO_PI_OVER_N * (float)tid, &sv, &cv);
        cs[tid] = cv; sn[tid] = sv;
    }
    const size_t base = (((size_t)b * H_DIM) * WF + kw) * C_DIM + c0;
    const size_t hstr = (size_t)WF * C_DIM;
    for (int idx = tid; idx < H_DIM * 32; idx += 256) {
        int h = idx >> 5, c = idx & 31;
        zs[h][c] = S[base + (size_t)h * hstr + c];
    }
    __syncthreads();

    const int c  = tid & 31;
    const int j0 = tid >> 5;             // 0..7
    #pragma unroll
    for (int s = 0; s < 7; ++s) {
        const int ls = INV ? s : (6 - s);
        const int m  = 1 << ls;
        #pragma unroll
        for (int jj = 0; jj < 8; ++jj) {
            const int j  = j0 + jj * 8;
            const int t  = j & (m - 1);
            const int i0 = 2 * j - t;
            const int i1 = i0 + m;
            const int tw = t << (6 - ls);
            float2 a  = zs[i0][c];
            float2 bv = zs[i1][c];
            const float cv = cs[tw], sv = sn[tw];
            if (!INV) {
                float dx = a.x - bv.x, dy = a.y - bv.y;
                zs[i0][c] = make_float2(a.x + bv.x, a.y + bv.y);
                zs[i1][c] = make_float2(fmaf(dx, cv,  dy * sv),
                                        fmaf(dy, cv, -dx * sv));
            } else {
                float btx = fmaf(bv.x, cv, -bv.y * sv);
                float bty = fmaf(bv.y, cv,  bv.x * sv);
                zs[i0][c] = make_float2(a.x + btx, a.y + bty);
                zs[i1][c] = make_float2(a.x - btx, a.y - bty);
            }
        }
        __syncthreads();
    }

    for (int idx = tid; idx < H_DIM * 32; idx += 256) {
        int h = idx >> 5, cc = idx & 31;
        float2 v = zs[h][cc];
        if (INV) { v.x *= 0.0078125f; v.y *= 0.0078125f; }
        S[base + (size_t)h * hstr + cc] = v;
    }
}

// ---------------------------------------------------------------------------
// K3: MLP on matrix cores. Real GEMM view: A[128 x 192] = [x_r | x_i],
// B[192 x 192] = [B_r | B_i], C = [o_r | o_i]. bf16 split-2, 3 passes
// (Ah*Bh + Ah*Bl + Al*Bh), fp32 accum. A in LDS (stride 200: 2-way banks),
// B-frags streamed from L2 (1.2 MB resident).
// grid: (520, 8) ; block 512 (8 waves: 4 M-tiles x 2 N-halves)
// ---------------------------------------------------------------------------
__device__ __forceinline__ float softshrinkf(float v) {
    return v > LAMBDA ? v - LAMBDA : (v < -LAMBDA ? v + LAMBDA : 0.f);
}

__global__ __launch_bounds__(512, 2) void k3_mfma(float2* __restrict__ S,
                                                  const short* __restrict__ bt,
                                                  const float* __restrict__ b1,
                                                  const float* __restrict__ b2) {
    const int n     = blockIdx.y;
    const int pbase = blockIdx.x * 128;
    const int c0    = n * BS;

    __shared__ short Ah[128][200];   // 51200 B  (rows stride 400 B -> 2-way banks)
    __shared__ short Al[128][200];   // 51200 B

    const int tid  = threadIdx.x;
    const int lane = tid & 63;
    const int wv   = tid >> 6;       // 0..7
    const int wm   = wv >> 1;        // 0..3 : M-tile of 32 rows
    const int wn   = wv & 1;         // 0..1 : N-half (0: o_r, 1: o_i)
    const int l15  = lane & 15;
    const int lk8  = (lane >> 4) * 8;
    const int lr4  = (lane >> 4) * 4;

    // ---- stage A1 = [Re | Im] as bf16 hi/lo --------------------------------
    for (int idx = tid; idx < 128 * 96; idx += 512) {
        int m = idx / 96, c = idx - m * 96;
        float2 z = S[(size_t)(pbase + m) * C_DIM + c0 + c];
        short h, l;
        split_bf16(z.x, h, l); Ah[m][c]      = h; Al[m][c]      = l;
        split_bf16(z.y, h, l); Ah[m][96 + c] = h; Al[m][96 + c] = l;
    }
    __syncthreads();

    // ---- layer 1 -----------------------------------------------------------
    const short* bt1h = bt + ((size_t)((0 * 8 + n) * 2 + wn) * 2 + 0) * 18432;
    const short* bt1l = bt1h + 18432;
    const short* bt2h = bt + ((size_t)((1 * 8 + n) * 2 + wn) * 2 + 0) * 18432;
    const short* bt2l = bt2h + 18432;

    f32x4 acc[2][6];
    #pragma unroll
    for (int ma = 0; ma < 2; ++ma)
        #pragma unroll
        for (int nb = 0; nb < 6; ++nb) acc[ma][nb] = (f32x4){0.f, 0.f, 0.f, 0.f};

    for (int ks = 0; ks < 6; ++ks) {
        const int koff = ks * 32 + lk8;
        bf16x8 ah[2], al[2];
        #pragma unroll
        for (int ma = 0; ma < 2; ++ma) {
            const int row = wm * 32 + ma * 16 + l15;
            ah[ma] = *(const bf16x8*)&Ah[row][koff];
            al[ma] = *(const bf16x8*)&Al[row][koff];
        }
        bf16x8 bh[6], bl[6];
        #pragma unroll
        for (int nb = 0; nb < 6; ++nb) {
            const int cl = nb * 16 + l15;
            bh[nb] = *(const bf16x8*)(bt1h + cl * 192 + koff);
            bl[nb] = *(const bf16x8*)(bt1l + cl * 192 + koff);
        }
        #pragma unroll
        for (int ma = 0; ma < 2; ++ma)
            #pragma unroll
            for (int nb = 0; nb < 6; ++nb) {
                acc[ma][nb] = __builtin_amdgcn_mfma_f32_16x16x32_bf16(ah[ma], bh[nb], acc[ma][nb], 0, 0, 0);
                acc[ma][nb] = __builtin_amdgcn_mfma_f32_16x16x32_bf16(ah[ma], bl[nb], acc[ma][nb], 0, 0, 0);
                acc[ma][nb] = __builtin_amdgcn_mfma_f32_16x16x32_bf16(al[ma], bh[nb], acc[ma][nb], 0, 0, 0);
            }
    }
    __syncthreads();   // all waves done READING A1

    // ---- epilogue 1: bias + relu -> re-split into A buffers ---------------
    {
        const float* b1p = b1 + (size_t)(wn * 8 + n) * 96;
        #pragma unroll
        for (int ma = 0; ma < 2; ++ma)
            #pragma unroll
            for (int nb = 0; nb < 6; ++nb) {
                const int cl = nb * 16 + l15;
                const float bb = b1p[cl];
                const int kdst = wn * 96 + cl;
                #pragma unroll
                for (int j = 0; j < 4; ++j) {
                    const int row = wm * 32 + ma * 16 + lr4 + j;
                    float v = fmaxf(acc[ma][nb][j] + bb, 0.f);
                    short h, l; split_bf16(v, h, l);
                    Ah[row][kdst] = h; Al[row][kdst] = l;
                }
            }
    }
    __syncthreads();

    // ---- layer 2 -----------------------------------------------------------
    #pragma unroll
    for (int ma = 0; ma < 2; ++ma)
        #pragma unroll
        for (int nb = 0; nb < 6; ++nb) acc[ma][nb] = (f32x4){0.f, 0.f, 0.f, 0.f};

    for (int ks = 0; ks < 6; ++ks) {
        const int koff = ks * 32 + lk8;
        bf16x8 ah[2], al[2];
        #pragma unroll
        for (int ma = 0; ma < 2; ++ma) {
            const int row = wm * 32 + ma * 16 + l15;
            ah[ma] = *(const bf16x8*)&Ah[row][koff];
            al[ma] = *(const bf16x8*)&Al[row][koff];
        }
        bf16x8 bh[6], bl[6];
        #pragma unroll
        for (int nb = 0; nb < 6; ++nb) {
            const int cl = nb * 16 + l15;
            bh[nb] = *(const bf16x8*)(bt2h + cl * 192 + koff);
            bl[nb] = *(const bf16x8*)(bt2l + cl * 192 + koff);
        }
        #pragma unroll
        for (int ma = 0; ma < 2; ++ma)
            #pragma unroll
            for (int nb = 0; nb < 6; ++nb) {
                acc[ma][nb] = __builtin_amdgcn_mfma_f32_16x16x32_bf16(ah[ma], bh[nb], acc[ma][nb], 0, 0, 0);
                acc[ma][nb] = __builtin_amdgcn_mfma_f32_16x16x32_bf16(ah[ma], bl[nb], acc[ma][nb], 0, 0, 0);
                acc[ma][nb] = __builtin_amdgcn_mfma_f32_16x16x32_bf16(al[ma], bh[nb], acc[ma][nb], 0, 0, 0);
            }
    }

    // ---- epilogue 2: bias + softshrink -> store (Re to .x / Im to .y) -----
    {
        const float* b2p = b2 + (size_t)(wn * 8 + n) * 96;
        #pragma unroll
        for (int ma = 0; ma < 2; ++ma)
            #pragma unroll
            for (int nb = 0; nb < 6; ++nb) {
                const int cl = nb * 16 + l15;
                const float bb = b2p[cl];
                #pragma unroll
                for (int j = 0; j < 4; ++j) {
                    const int row = wm * 32 + ma * 16 + lr4 + j;
                    float v = softshrinkf(acc[ma][nb][j] + bb);
                    float* dst = (float*)(S + (size_t)(pbase + row) * C_DIM + c0 + cl) + wn;
                    *dst = v;
                }
            }
    }
}

// ---------------------------------------------------------------------------
// K5: C2R inverse rfft along W via packed complex radix-2 FFT, + bias add.
// grid: (B*H) * 24 ; block 256
// ---------------------------------------------------------------------------
__global__ __launch_bounds__(256) void k5_irfft_w(const float2* __restrict__ S,
                                                  const float* __restrict__ x,
                                                  float* __restrict__ out) {
    const int blk   = blockIdx.x;
    const int ctile = blk % 24;
    const int bh    = blk / 24;
    const int c0    = ctile * 32;

    __shared__ float2 zs[W_DIM][17];
    __shared__ float cs[64], sn[64];

    const int tid = threadIdx.x;
    if (tid < 64) {
        float sv, cv;
        sincosf(TWO_PI_OVER_N * (float)tid, &sv, &cv);
        cs[tid] = cv; sn[tid] = sv;
    }
    for (int pos = tid; pos < WF * 16; pos += 256) {
        int kw = pos >> 4, uu = pos & 15;
        float4 q = ((const float4*)(S + ((size_t)bh * WF + kw) * C_DIM + c0))[uu];
        float xcx = q.x, xcy = q.y, xdx = q.z, xdy = q.w;
        if (kw == 0 || kw == 64) { xcy = 0.f; xdy = 0.f; }
        zs[kw][uu] = make_float2(xcx - xdy, xcy + xdx);
        if (kw >= 1 && kw <= 63)
            zs[128 - kw][uu] = make_float2(xcx + xdy, xdx - xcy);
    }
    __syncthreads();

    const int u  = tid & 15;
    const int j0 = tid >> 4;
    #pragma unroll
    for (int s = 0; s < 7; ++s) {
        const int ls = 6 - s;
        const int m  = 1 << ls;
        #pragma unroll
        for (int jj = 0; jj < 4; ++jj) {
            const int j  = j0 + jj * 16;
            const int t  = j & (m - 1);
            const int i0 = 2 * j - t;
            const int i1 = i0 + m;
            const int tw = t << (6 - ls);
            float2 a = zs[i0][u], b = zs[i1][u];
            const float cv = cs[tw], sv = sn[tw];
            float dx = a.x - b.x, dy = a.y - b.y;
            zs[i0][u] = make_float2(a.x + b.x, a.y + b.y);
            zs[i1][u] = make_float2(fmaf(dx, cv, -dy * sv),
                                    fmaf(dy, cv,  dx * sv));
        }
        __syncthreads();
    }

    const size_t obase = (size_t)bh * (W_DIM * C_DIM) + c0;
    for (int pos = tid; pos < W_DIM * 16; pos += 256) {
        int p = pos >> 4, uu = pos & 15;
        int w = brev7(p);
        float2 v  = zs[p][uu];
        float2 xv = ((const float2*)(x + obase + (size_t)w * C_DIM))[uu];
        ((float2*)(out + obase + (size_t)w * C_DIM))[uu] =
            make_float2(v.x + xv.x, v.y + xv.y);
    }
}

// ---------------------------------------------------------------------------
extern "C" void kernel_launch(void* const* d_in, const int* in_sizes, int n_in,
                              void* d_out, int out_size, void* d_ws, size_t ws_size,
                              hipStream_t stream) {
    const float* x  = (const float*)d_in[0];
    const float* w1 = (const float*)d_in[1];
    const float* b1 = (const float*)d_in[2];
    const float* w2 = (const float*)d_in[3];
    const float* b2 = (const float*)d_in[4];
    float* out = (float*)d_out;
    float2* S  = (float2*)d_ws;          // (B,H,WF,C) complex64 = 409 MB
    short* bt  = (short*)d_out;          // 2.4 MB weight scratch, overwritten by k5

    k0_wconv<<<dim3(2304), dim3(256), 0, stream>>>(w1, w2, bt);
    k1_rfft_w<<<dim3(B_DIM * H_DIM * 24), dim3(256), 0, stream>>>(x, S);
    k_fft_h<false><<<dim3(B_DIM * WF * 24), dim3(256), 0, stream>>>(S);
    k3_mfma<<<dim3((B_DIM * H_DIM * WF) / 128, NBLK), dim3(512), 0, stream>>>(S, bt, b1, b2);
    k_fft_h<true><<<dim3(B_DIM * WF * 24), dim3(256), 0, stream>>>(S);
    k5_irfft_w<<<dim3(B_DIM * H_DIM * 24), dim3(256), 0, stream>>>(S, x, out);
}